// Round 5
// baseline (4444.355 us; speedup 1.0000x reference)
//
#include <hip/hip_runtime.h>
#include <hip/hip_bf16.h>

#define B_ 32
#define T_ 512
#define E_ 256
#define H_ 512
#define L_ 50
#define NBLK 32          // worker blocks
#define NGRID 256        // workers + clock-pin burners

typedef __attribute__((ext_vector_type(8))) short short8;
typedef __attribute__((ext_vector_type(4))) float v4f;
typedef unsigned long long u64;

__device__ __forceinline__ unsigned short f2bf(float f){
    union { float f; unsigned u; } v; v.f = f;
    unsigned u = v.u;
    u += 0x7fffu + ((u >> 16) & 1u);   // RNE
    return (unsigned short)(u >> 16);
}
__device__ __forceinline__ float sigf(float x){ return 1.0f / (1.0f + expf(-x)); }

__device__ __forceinline__ float qredmax(float v){
    v = fmaxf(v, __shfl_xor(v, 1, 64));
    v = fmaxf(v, __shfl_xor(v, 2, 64));
    v = fmaxf(v, __shfl_xor(v, 4, 64));
    v = fmaxf(v, __shfl_xor(v, 8, 64));
    return v;
}
__device__ __forceinline__ float qredsum(float v){
    v += __shfl_xor(v, 1, 64);
    v += __shfl_xor(v, 2, 64);
    v += __shfl_xor(v, 4, 64);
    v += __shfl_xor(v, 8, 64);
    return v;
}

// ---------------------------------------------------------------- init
__global__ void init_kernel(const float* __restrict__ projW,
                            float* __restrict__ out,
                            unsigned int* __restrict__ cnt,     // [0]=done, rest scratch
                            unsigned int* __restrict__ flags,   // [T_][NBLK]
                            unsigned short* __restrict__ h0,
                            unsigned short* __restrict__ Wt)
{
    const int i = blockIdx.x * 256 + threadIdx.x;   // grid covers 32768
    if (i < 1024) cnt[i] = 0u;
    if (i < T_ * NBLK) flags[i] = 0u;
    if (i == 0) out[0] = 0.f;
    if (i < B_ * H_) h0[i] = 0;                     // h_all step 0 = zeros
    if (i < 64 * H_){                               // Wt[c][k] = proj_W[k][c], bf16, pad c>=50 with 0
        const int c = i >> 9;
        const int k = i & 511;
        const float v = (c < L_) ? projW[k * L_ + c] : 0.f;
        Wt[i] = f2bf(v);
    }
}

// ---------------------------------------------------------------- LSTM recurrence (cooperative)
// Workers (blocks 0..31): identical to round 4 — write-through h production
// (sc0sc1 + vmcnt drain + bypass flag), cached 16B h consumption.
// Burners (blocks 32..255): dependent-FMA spin to pin the GFX clock at fmax
// (round-2/4 cold-dispatch evidence: 36-45 ms first call => deep DVFS downclock;
// steady-state model fits measurement only at ~500 MHz). Unlike round 3, the
// burner poll is ONE agent-scope load per block per ~13 us (tid0 -> LDS
// broadcast), so the fabric/L3 sync path is not polluted.
__global__ void __launch_bounds__(512, 2) lstm_kernel(
    const int* __restrict__ q, const int* __restrict__ lengths,
    const float* __restrict__ we, const float* __restrict__ lstmW,
    const float* __restrict__ lstmB,
    unsigned short* __restrict__ h_all, unsigned int* __restrict__ flags,
    unsigned int* __restrict__ done, float* __restrict__ sink)
{
    const int tid  = threadIdx.x;
    const int blk  = blockIdx.x;

    if (blk >= NBLK){
        // -------- clock-pin burner: heavy VALU, ~1 fabric poll / 13 us / block
        __shared__ unsigned stop;
        if (tid == 0) stop = 0u;
        __syncthreads();
        float x = (float)tid + 1.0f;
        for (int outer = 0; outer < 4096; ++outer){       // hard cap ~56 ms
            for (int i = 0; i < 8192; ++i)                // ~32K cycles dependent FMA
                x = __builtin_fmaf(x, 0.99999988f, 1.0e-7f);
            if (tid == 0 &&
                __hip_atomic_load(done, __ATOMIC_RELAXED, __HIP_MEMORY_SCOPE_AGENT) >= NBLK)
                stop = 1u;
            __syncthreads();
            if (stop) break;
        }
        if (x == 1.2345e33f) sink[0] = x;                 // defeat DCE; never taken
        return;
    }

    const int wv   = tid >> 6;          // 0..7
    const int lane = tid & 63;
    const int nt = wv & 1, mt = wv >> 1;  // mt 0..3
    const int l15 = lane & 15, quad = lane >> 4;

    // ---- A-operand mapping (lane&15 = m = z-col in tile; k = quad*8 + j)
    const int hcA  = blk * 16 + mt * 4 + (l15 >> 2);
    const int gA   = l15 & 3;
    const int colA = gA * H_ + hcA;     // column in lstm_W [768][2048]

    short8 AW[8], AH[16];
#pragma unroll
    for (int kc = 0; kc < 8; ++kc){     // x-part rows 0..255
        short8 f;
#pragma unroll
        for (int j = 0; j < 8; ++j){
            const int r = kc * 32 + quad * 8 + j;
            f[j] = (short)f2bf(lstmW[(size_t)r * 2048 + colA]);
        }
        AW[kc] = f;
    }
#pragma unroll
    for (int kc = 0; kc < 16; ++kc){    // h-part rows 256..767
        short8 f;
#pragma unroll
        for (int j = 0; j < 8; ++j){
            const int r = E_ + kc * 32 + quad * 8 + j;
            f[j] = (short)f2bf(lstmW[(size_t)r * 2048 + colA]);
        }
        AH[kc] = f;
    }

    // ---- epilogue mapping (lane&15 = n = batch; D row quad*4+reg -> hc=quad, gate=reg)
    const int bE  = nt * 16 + l15;
    const int hcE = blk * 16 + mt * 4 + quad;
    float bias4[4];
#pragma unroll
    for (int g = 0; g < 4; ++g) bias4[g] = lstmB[g * H_ + hcE];
    const int lenb = lengths[bE];

    float c_state = 0.f, h_prev = 0.f;

    // pre-loop x-part for t=0 (embedding gather + Wx MFMAs)
    v4f accX = { bias4[0], bias4[1], bias4[2], bias4[3] };
    {
        const int qv = q[bE * T_];
        const v4f* wp = (const v4f*)(we + (size_t)qv * E_);
#pragma unroll
        for (int kc = 0; kc < 8; ++kc){
            const v4f e0 = wp[kc * 8 + quad * 2];
            const v4f e1 = wp[kc * 8 + quad * 2 + 1];
            short8 eb;
#pragma unroll
            for (int j = 0; j < 4; ++j){ eb[j] = (short)f2bf(e0[j]); eb[4 + j] = (short)f2bf(e1[j]); }
            accX = __builtin_amdgcn_mfma_f32_16x16x32_bf16(AW[kc], eb, accX, 0, 0, 0);
        }
    }

    for (int t = 0; t < T_; ++t){
        if (t > 0){
            // per-wave flag poll: lanes 0..31 each watch one producer's flag (bypass loads)
            const unsigned int* fl = flags + (unsigned)(t - 1) * NBLK;
            int guard = 0;
            for (;;){
                unsigned f = 1u;
                if (lane < NBLK)
                    f = __hip_atomic_load(fl + lane, __ATOMIC_RELAXED, __HIP_MEMORY_SCOPE_AGENT);
                if (__ballot(f != 0u) == 0xFFFFFFFFFFFFFFFFull) break;
                __builtin_amdgcn_s_sleep(1);
                if (++guard > (1 << 24)) break;   // safety valve
            }
            __builtin_amdgcn_fence(__ATOMIC_ACQUIRE, "workgroup");  // ordering only (no cache ops)
        }

        // h-part B-frags: normal cached 16B loads (L2-miss pulls fresh L3 data;
        // lines are never stale-resident: written only via L2-bypass stores)
        const unsigned short* hrow = h_all + (size_t)t * (B_ * H_) + (size_t)bE * H_;
        v4f acc = accX, acc2 = { 0.f, 0.f, 0.f, 0.f };   // two chains halve MFMA dep latency
#pragma unroll
        for (int kc = 0; kc < 16; ++kc){
            const short8 hb = *(const short8*)(hrow + kc * 32 + quad * 8);
            if (kc & 1) acc2 = __builtin_amdgcn_mfma_f32_16x16x32_bf16(AH[kc], hb, acc2, 0, 0, 0);
            else        acc  = __builtin_amdgcn_mfma_f32_16x16x32_bf16(AH[kc], hb, acc,  0, 0, 0);
        }

        // gates: i,j,f,o = acc[0..3]
        const float gi = acc[0] + acc2[0], gj = acc[1] + acc2[1];
        const float gf = acc[2] + acc2[2], go = acc[3] + acc2[3];
        const float c_new = c_state * sigf(gf + 1.0f) + sigf(gi) * tanhf(gj);
        const float h_new = tanhf(c_new) * sigf(go);
        const bool msk = (t < lenb);
        c_state = msk ? c_new : c_state;
        const float h2 = msk ? h_new : h_prev;           // dynamic_rnn copy-through
        h_prev = h2;

        // pack 4 hc (one per quad, same batch) into one u64, write-through to L3
        const unsigned hv = f2bf(h2);
        const int v0 = __shfl((int)hv, l15,      64);
        const int v1 = __shfl((int)hv, l15 + 16, 64);
        const int v2 = __shfl((int)hv, l15 + 32, 64);
        const int v3 = __shfl((int)hv, l15 + 48, 64);
        if (quad == 0){
            const u64 pk = (u64)(unsigned short)v0
                         | ((u64)(unsigned short)v1 << 16)
                         | ((u64)(unsigned short)v2 << 32)
                         | ((u64)(unsigned short)v3 << 48);
            u64* dst = (u64*)(h_all + (size_t)(t + 1) * (B_ * H_) + (size_t)bE * H_ + blk * 16 + mt * 4);
            __hip_atomic_store(dst, pk, __ATOMIC_RELAXED, __HIP_MEMORY_SCOPE_AGENT);
        }
        asm volatile("s_waitcnt vmcnt(0)" ::: "memory");  // h stores ack'd at L3
        __syncthreads();                                  // all waves of block done
        if (tid == 0)
            __hip_atomic_store(&flags[(unsigned)t * NBLK + blk], 1u,
                               __ATOMIC_RELAXED, __HIP_MEMORY_SCOPE_AGENT);

        // tail (in notify slack): x-part for t+1 (normal cached loads)
        if (t + 1 < T_){
            accX = (v4f){ bias4[0], bias4[1], bias4[2], bias4[3] };
            const int qv = q[bE * T_ + t + 1];
            const v4f* wp = (const v4f*)(we + (size_t)qv * E_);
#pragma unroll
            for (int kc = 0; kc < 8; ++kc){
                const v4f e0 = wp[kc * 8 + quad * 2];
                const v4f e1 = wp[kc * 8 + quad * 2 + 1];
                short8 eb;
#pragma unroll
                for (int j = 0; j < 4; ++j){ eb[j] = (short)f2bf(e0[j]); eb[4 + j] = (short)f2bf(e1[j]); }
                accX = __builtin_amdgcn_mfma_f32_16x16x32_bf16(AW[kc], eb, accX, 0, 0, 0);
            }
        }
    }

    if (tid == 0)
        __hip_atomic_fetch_add(done, 1u, __ATOMIC_RELAXED, __HIP_MEMORY_SCOPE_AGENT);
}

// ---------------------------------------------------------------- projection + relu + log-softmax + xent
__global__ void __launch_bounds__(256) loss_kernel(
    const int* __restrict__ a, const int* __restrict__ lengths,
    const float* __restrict__ projB,
    const unsigned short* __restrict__ h_all,
    const unsigned short* __restrict__ Wt,
    float* __restrict__ out)
{
    const int tid = threadIdx.x;
    const int wv = tid >> 6, lane = tid & 63;
    const int l15 = lane & 15, quad = lane >> 4;
    const int wgid = blockIdx.x * 4 + wv;            // 0..1023
    const int row0 = wgid * 16;

    const int rowA = row0 + l15;
    const int bA = rowA >> 9, tA = rowA & 511;
    const unsigned short* hrow = h_all + ((size_t)(tA + 1) * B_ + bA) * H_;

    v4f acc[4] = { {0,0,0,0}, {0,0,0,0}, {0,0,0,0}, {0,0,0,0} };
#pragma unroll
    for (int kc = 0; kc < 16; ++kc){
        const short8 af = *(const short8*)(hrow + kc * 32 + quad * 8);
#pragma unroll
        for (int ntl = 0; ntl < 4; ++ntl){
            const short8 bf = *(const short8*)(Wt + (size_t)(ntl * 16 + l15) * H_ + kc * 32 + quad * 8);
            acc[ntl] = __builtin_amdgcn_mfma_f32_16x16x32_bf16(af, bf, acc[ntl], 0, 0, 0);
        }
    }

    float pb[4]; bool cv[4];
#pragma unroll
    for (int ntl = 0; ntl < 4; ++ntl){
        const int c = ntl * 16 + l15;
        cv[ntl] = (c < L_);
        pb[ntl] = cv[ntl] ? projB[c] : 0.f;
    }

#pragma unroll
    for (int r = 0; r < 4; ++r){
        const int row = row0 + quad * 4 + r;
        const int b = row >> 9, t = row & 511;
        const int len = lengths[b];
        const bool valid = (t < len);

        float lv[4];
#pragma unroll
        for (int ntl = 0; ntl < 4; ++ntl)
            lv[ntl] = fmaxf(acc[ntl][r] + pb[ntl], 0.f);   // relu(logits)

        float mx = -1e30f;
#pragma unroll
        for (int ntl = 0; ntl < 4; ++ntl) if (cv[ntl]) mx = fmaxf(mx, lv[ntl]);
        mx = qredmax(mx);
        float se = 0.f;
#pragma unroll
        for (int ntl = 0; ntl < 4; ++ntl) if (cv[ntl]) se += expf(lv[ntl] - mx);
        se = qredsum(se);
        const int lbl = a[row];
        float cand = 0.f;
#pragma unroll
        for (int ntl = 0; ntl < 4; ++ntl) if (ntl * 16 + l15 == lbl) cand = lv[ntl];
        const float llbl = qredsum(cand);

        if (valid && l15 == 0){
            const float xent = logf(se) + mx - llbl;      // -log_softmax[label]
            atomicAdd(out, xent / ((float)len * 32.0f));
        }
    }
}

// ---------------------------------------------------------------- launch
extern "C" void kernel_launch(void* const* d_in, const int* in_sizes, int n_in,
                              void* d_out, int out_size, void* d_ws, size_t ws_size,
                              hipStream_t stream)
{
    const int*   q   = (const int*)d_in[0];
    const int*   a   = (const int*)d_in[1];
    const int*   len = (const int*)d_in[2];
    const float* we  = (const float*)d_in[3];
    const float* lW  = (const float*)d_in[4];
    const float* lB  = (const float*)d_in[5];
    const float* pW  = (const float*)d_in[6];
    const float* pB  = (const float*)d_in[7];
    float* out = (float*)d_out;

    unsigned char* ws = (unsigned char*)d_ws;
    unsigned int*   cnt   = (unsigned int*)ws;                       // 4 KiB: [0]=done, [512..]=sink
    unsigned int*   flags = (unsigned int*)(ws + 4096);              // 512*32*4 = 64 KiB
    unsigned short* h_all = (unsigned short*)(ws + 4096 + 65536);    // 513*32*512*2 B
    unsigned short* Wt    = (unsigned short*)(ws + 4096 + 65536 + (size_t)(T_ + 1) * B_ * H_ * 2);

    init_kernel<<<dim3(128), dim3(256), 0, stream>>>(pW, out, cnt, flags, h_all, Wt);

    {
        const int* q_ = q; const int* len_ = len; const float* we_ = we;
        const float* lW_ = lW; const float* lB_ = lB;
        unsigned short* h_ = h_all; unsigned int* f_ = flags;
        unsigned int* d_ = cnt; float* s_ = (float*)(cnt + 512);
        void* args[] = { (void*)&q_, (void*)&len_, (void*)&we_, (void*)&lW_,
                         (void*)&lB_, (void*)&h_, (void*)&f_, (void*)&d_, (void*)&s_ };
        hipLaunchCooperativeKernel((void*)lstm_kernel, dim3(NGRID), dim3(512),
                                   args, 0, stream);
    }

    loss_kernel<<<dim3(256), dim3(256), 0, stream>>>(a, len, pB, h_all, Wt, out);
}

// Round 6
// 3750.893 us; speedup vs baseline: 1.1849x; 1.1849x over previous
//
#include <hip/hip_runtime.h>
#include <hip/hip_bf16.h>

#define B_ 32
#define T_ 512
#define E_ 256
#define H_ 512
#define L_ 50
#define NBLK 32          // worker blocks (all on ONE XCD)
#define NGRID 256        // launched blocks; non-winners exit

typedef __attribute__((ext_vector_type(8))) short short8;
typedef __attribute__((ext_vector_type(4))) float v4f;
typedef __attribute__((ext_vector_type(4))) int i4;
typedef unsigned long long u64;

__device__ __forceinline__ unsigned short f2bf(float f){
    union { float f; unsigned u; } v; v.f = f;
    unsigned u = v.u;
    u += 0x7fffu + ((u >> 16) & 1u);   // RNE
    return (unsigned short)(u >> 16);
}
__device__ __forceinline__ float sigf(float x){ return 1.0f / (1.0f + expf(-x)); }

__device__ __forceinline__ float qredmax(float v){
    v = fmaxf(v, __shfl_xor(v, 1, 64));
    v = fmaxf(v, __shfl_xor(v, 2, 64));
    v = fmaxf(v, __shfl_xor(v, 4, 64));
    v = fmaxf(v, __shfl_xor(v, 8, 64));
    return v;
}
__device__ __forceinline__ float qredsum(float v){
    v += __shfl_xor(v, 1, 64);
    v += __shfl_xor(v, 2, 64);
    v += __shfl_xor(v, 4, 64);
    v += __shfl_xor(v, 8, 64);
    return v;
}

// sc0-only memory ops: bypass L1, hit the XCD-shared L2 (intra-XCD coherent).
__device__ __forceinline__ i4 load16_sc0(const void* p){
    i4 r;
    asm volatile("global_load_dwordx4 %0, %1, off sc0" : "=v"(r) : "v"(p) : "memory");
    return r;
}
__device__ __forceinline__ void store8_sc0(void* p, u64 v){
    asm volatile("global_store_dwordx2 %0, %1, off sc0" : : "v"(p), "v"(v) : "memory");
}
__device__ __forceinline__ void store4_sc0(void* p, unsigned v){
    asm volatile("global_store_dword %0, %1, off sc0" : : "v"(p), "v"(v) : "memory");
}
__device__ __forceinline__ unsigned load4_sc0_wait(const void* p){
    unsigned r;
    asm volatile("global_load_dword %0, %1, off sc0\n\ts_waitcnt vmcnt(0)"
                 : "=v"(r) : "v"(p) : "memory");
    return r;
}
__device__ __forceinline__ void wait_vm0(){
    asm volatile("s_waitcnt vmcnt(0)" ::: "memory");
}

// ---------------------------------------------------------------- init
__global__ void init_kernel(const float* __restrict__ projW,
                            float* __restrict__ out,
                            unsigned int* __restrict__ setup,   // [0]=winner, [1..8]=xcd tickets
                            unsigned int* __restrict__ flags,   // [T_][NBLK]
                            unsigned short* __restrict__ h0,
                            unsigned short* __restrict__ Wt)
{
    const int i = blockIdx.x * 256 + threadIdx.x;   // grid covers 32768
    if (i < 1024) setup[i] = 0u;
    if (i < T_ * NBLK) flags[i] = 0u;
    if (i == 0) out[0] = 0.f;
    if (i < B_ * H_) h0[i] = 0;                     // h_all step 0 = zeros
    if (i < 64 * H_){                               // Wt[c][k] = proj_W[k][c], bf16, pad c>=50 with 0
        const int c = i >> 9;
        const int k = i & 511;
        const float v = (c < L_) ? projW[k * L_ + c] : 0.f;
        Wt[i] = f2bf(v);
    }
}

// ---------------------------------------------------------------- LSTM recurrence (cooperative, single-XCD)
// 256 blocks launched; each reads HW_REG_XCC_ID and tickets per-XCD. First XCD
// to collect 32 blocks elects itself winner (CAS); its first 32 blocks are the
// workers, everyone else exits. Pigeonhole (256 blocks / 8 XCDs) guarantees a
// winner regardless of dispatch policy -> correctness never depends on placement.
// All h-exchange / flags use sc0-only ops through the winner XCD's shared L2
// (~200cy RT) instead of cross-XCD fabric (~1-2Kcy) — rounds 1-5 showed the
// fabric round-trips x skew were the 8-12us/step wall.
// Work split: 32 blocks x 4 waves; wave = 2 m-tiles x 1 n-half (B loaded once,
// used by both tiles). z-col permutation c=4*hc+gate puts gates i,j,f,o of one
// (b,hc) in one lane's acc[0..3] (verified rounds 1-5).
__global__ void __launch_bounds__(256, 1) lstm_kernel(
    const int* __restrict__ q, const int* __restrict__ lengths,
    const float* __restrict__ we, const float* __restrict__ lstmW,
    const float* __restrict__ lstmB,
    unsigned short* __restrict__ h_all, unsigned int* __restrict__ flags,
    unsigned int* __restrict__ setup)
{
    const int tid  = threadIdx.x;

    __shared__ int s_role;
    if (tid == 0){
        int xcd;
        asm volatile("s_getreg_b32 %0, hwreg(HW_REG_XCC_ID)" : "=s"(xcd));
        xcd &= 7;
        unsigned tk = __hip_atomic_fetch_add(&setup[1 + xcd], 1u,
                                             __ATOMIC_RELAXED, __HIP_MEMORY_SCOPE_AGENT);
        int role = -1;
        if (tk < (unsigned)NBLK){
            if (tk == NBLK - 1){
                unsigned exp = 0u;
                __hip_atomic_compare_exchange_strong(&setup[0], &exp, (unsigned)(xcd + 1),
                    __ATOMIC_RELAXED, __ATOMIC_RELAXED, __HIP_MEMORY_SCOPE_AGENT);
            }
            unsigned w = 0u; int guard = 0;
            for (;;){
                w = __hip_atomic_load(&setup[0], __ATOMIC_RELAXED, __HIP_MEMORY_SCOPE_AGENT);
                if (w != 0u || ++guard > (1 << 24)) break;
                __builtin_amdgcn_s_sleep(2);
            }
            if (w == (unsigned)(xcd + 1)) role = (int)tk;
        }
        s_role = role;
    }
    __syncthreads();
    const int blk = s_role;          // worker slot 0..31, or -1
    if (blk < 0) return;

    const int wv   = tid >> 6;       // 0..3
    const int lane = tid & 63;
    const int nt = wv & 1, mpair = wv >> 1;   // n-half, m-tile pair
    const int l15 = lane & 15, quad = lane >> 4;

    // ---- A-operand mapping (lane&15 = m = z-col in tile; k = quad*8 + j)
    const int hcA0 = blk * 16 + (mpair * 2 + 0) * 4 + (l15 >> 2);
    const int hcA1 = blk * 16 + (mpair * 2 + 1) * 4 + (l15 >> 2);
    const int gA   = l15 & 3;
    const int colA0 = gA * H_ + hcA0;
    const int colA1 = gA * H_ + hcA1;

    short8 AW0[8], AW1[8], AH0[16], AH1[16];
#pragma unroll
    for (int kc = 0; kc < 8; ++kc){     // x-part rows 0..255
        short8 f0, f1;
#pragma unroll
        for (int j = 0; j < 8; ++j){
            const int r = kc * 32 + quad * 8 + j;
            f0[j] = (short)f2bf(lstmW[(size_t)r * 2048 + colA0]);
            f1[j] = (short)f2bf(lstmW[(size_t)r * 2048 + colA1]);
        }
        AW0[kc] = f0; AW1[kc] = f1;
    }
#pragma unroll
    for (int kc = 0; kc < 16; ++kc){    // h-part rows 256..767
        short8 f0, f1;
#pragma unroll
        for (int j = 0; j < 8; ++j){
            const int r = E_ + kc * 32 + quad * 8 + j;
            f0[j] = (short)f2bf(lstmW[(size_t)r * 2048 + colA0]);
            f1[j] = (short)f2bf(lstmW[(size_t)r * 2048 + colA1]);
        }
        AH0[kc] = f0; AH1[kc] = f1;
    }

    // ---- epilogue mapping (lane&15 = n = batch; D row quad*4+reg -> hc=quad, gate=reg)
    const int bE   = nt * 16 + l15;
    const int hcE0 = blk * 16 + (mpair * 2 + 0) * 4 + quad;
    const int hcE1 = blk * 16 + (mpair * 2 + 1) * 4 + quad;
    float bias0[4], bias1[4];
#pragma unroll
    for (int g = 0; g < 4; ++g){ bias0[g] = lstmB[g * H_ + hcE0]; bias1[g] = lstmB[g * H_ + hcE1]; }
    const int lenb = lengths[bE];

    float c0 = 0.f, c1 = 0.f, hp0 = 0.f, hp1 = 0.f;

    // pre-loop x-part for t=0
    v4f accX0 = { bias0[0], bias0[1], bias0[2], bias0[3] };
    v4f accX1 = { bias1[0], bias1[1], bias1[2], bias1[3] };
    {
        const int qv = q[bE * T_];
        const v4f* wp = (const v4f*)(we + (size_t)qv * E_);
#pragma unroll
        for (int kc = 0; kc < 8; ++kc){
            const v4f e0 = wp[kc * 8 + quad * 2];
            const v4f e1 = wp[kc * 8 + quad * 2 + 1];
            short8 eb;
#pragma unroll
            for (int j = 0; j < 4; ++j){ eb[j] = (short)f2bf(e0[j]); eb[4 + j] = (short)f2bf(e1[j]); }
            accX0 = __builtin_amdgcn_mfma_f32_16x16x32_bf16(AW0[kc], eb, accX0, 0, 0, 0);
            accX1 = __builtin_amdgcn_mfma_f32_16x16x32_bf16(AW1[kc], eb, accX1, 0, 0, 0);
        }
    }

    for (int t = 0; t < T_; ++t){
        if (t > 0){
            // poll 32 producer flags from XCD-local L2 (lanes 0..31)
            const unsigned int* fl = flags + (unsigned)(t - 1) * NBLK;
            int guard = 0;
            for (;;){
                unsigned f = 1u;
                if (lane < NBLK) f = load4_sc0_wait(fl + lane);
                if (__ballot(f != 0u) == 0xFFFFFFFFFFFFFFFFull) break;
                __builtin_amdgcn_s_sleep(1);
                if (++guard > (1 << 24)) break;   // safety valve
            }
        }

        // h B-frags from L2 (sc0), shared by both m-tiles; 2 groups of 8 kc
        const unsigned short* hrow = h_all + (size_t)t * (B_ * H_) + (size_t)bE * H_;
        v4f acc0 = accX0, acc1 = accX1;
#pragma unroll
        for (int g = 0; g < 2; ++g){
            i4 hbuf[8];
#pragma unroll
            for (int kc = 0; kc < 8; ++kc)
                hbuf[kc] = load16_sc0(hrow + (g * 8 + kc) * 32 + quad * 8);
            wait_vm0();
#pragma unroll
            for (int kc = 0; kc < 8; ++kc){
                union { i4 i; short8 s; } cv; cv.i = hbuf[kc];
                acc0 = __builtin_amdgcn_mfma_f32_16x16x32_bf16(AH0[g * 8 + kc], cv.s, acc0, 0, 0, 0);
                acc1 = __builtin_amdgcn_mfma_f32_16x16x32_bf16(AH1[g * 8 + kc], cv.s, acc1, 0, 0, 0);
            }
        }

        // gates per tile: i,j,f,o = acc[0..3]
        const bool msk = (t < lenb);
        const float cn0 = c0 * sigf(acc0[2] + 1.0f) + sigf(acc0[0]) * tanhf(acc0[1]);
        const float hn0 = tanhf(cn0) * sigf(acc0[3]);
        c0 = msk ? cn0 : c0;
        const float h20 = msk ? hn0 : hp0; hp0 = h20;
        const float cn1 = c1 * sigf(acc1[2] + 1.0f) + sigf(acc1[0]) * tanhf(acc1[1]);
        const float hn1 = tanhf(cn1) * sigf(acc1[3]);
        c1 = msk ? cn1 : c1;
        const float h21 = msk ? hn1 : hp1; hp1 = h21;

        // pack 4 hc per tile into u64; quad0 stores tile0, quad1 stores tile1
        const unsigned hv0 = f2bf(h20), hv1 = f2bf(h21);
        const int a0 = __shfl((int)hv0, l15, 64),      a1 = __shfl((int)hv0, l15 + 16, 64);
        const int a2 = __shfl((int)hv0, l15 + 32, 64), a3 = __shfl((int)hv0, l15 + 48, 64);
        const int b0 = __shfl((int)hv1, l15, 64),      b1 = __shfl((int)hv1, l15 + 16, 64);
        const int b2 = __shfl((int)hv1, l15 + 32, 64), b3 = __shfl((int)hv1, l15 + 48, 64);
        unsigned short* dstBase = h_all + (size_t)(t + 1) * (B_ * H_) + (size_t)bE * H_
                                + blk * 16 + mpair * 8;
        if (quad == 0){
            const u64 pk = (u64)(unsigned short)a0 | ((u64)(unsigned short)a1 << 16)
                         | ((u64)(unsigned short)a2 << 32) | ((u64)(unsigned short)a3 << 48);
            store8_sc0(dstBase, pk);
        } else if (quad == 1){
            const u64 pk = (u64)(unsigned short)b0 | ((u64)(unsigned short)b1 << 16)
                         | ((u64)(unsigned short)b2 << 32) | ((u64)(unsigned short)b3 << 48);
            store8_sc0(dstBase + 4, pk);
        }
        wait_vm0();                      // h stores committed in L2
        __syncthreads();                 // all waves of block done
        if (tid == 0)
            store4_sc0(&flags[(unsigned)t * NBLK + blk], 1u);

        // tail (in notify slack): x-part for t+1 (plain cached loads)
        if (t + 1 < T_){
            accX0 = (v4f){ bias0[0], bias0[1], bias0[2], bias0[3] };
            accX1 = (v4f){ bias1[0], bias1[1], bias1[2], bias1[3] };
            const int qv = q[bE * T_ + t + 1];
            const v4f* wp = (const v4f*)(we + (size_t)qv * E_);
#pragma unroll
            for (int kc = 0; kc < 8; ++kc){
                const v4f e0 = wp[kc * 8 + quad * 2];
                const v4f e1 = wp[kc * 8 + quad * 2 + 1];
                short8 eb;
#pragma unroll
                for (int j = 0; j < 4; ++j){ eb[j] = (short)f2bf(e0[j]); eb[4 + j] = (short)f2bf(e1[j]); }
                accX0 = __builtin_amdgcn_mfma_f32_16x16x32_bf16(AW0[kc], eb, accX0, 0, 0, 0);
                accX1 = __builtin_amdgcn_mfma_f32_16x16x32_bf16(AW1[kc], eb, accX1, 0, 0, 0);
            }
        }
    }
}

// ---------------------------------------------------------------- projection + relu + log-softmax + xent
__global__ void __launch_bounds__(256) loss_kernel(
    const int* __restrict__ a, const int* __restrict__ lengths,
    const float* __restrict__ projB,
    const unsigned short* __restrict__ h_all,
    const unsigned short* __restrict__ Wt,
    float* __restrict__ out)
{
    const int tid = threadIdx.x;
    const int wv = tid >> 6, lane = tid & 63;
    const int l15 = lane & 15, quad = lane >> 4;
    const int wgid = blockIdx.x * 4 + wv;            // 0..1023
    const int row0 = wgid * 16;

    const int rowA = row0 + l15;
    const int bA = rowA >> 9, tA = rowA & 511;
    const unsigned short* hrow = h_all + ((size_t)(tA + 1) * B_ + bA) * H_;

    v4f acc[4] = { {0,0,0,0}, {0,0,0,0}, {0,0,0,0}, {0,0,0,0} };
#pragma unroll
    for (int kc = 0; kc < 16; ++kc){
        const short8 af = *(const short8*)(hrow + kc * 32 + quad * 8);
#pragma unroll
        for (int ntl = 0; ntl < 4; ++ntl){
            const short8 bf = *(const short8*)(Wt + (size_t)(ntl * 16 + l15) * H_ + kc * 32 + quad * 8);
            acc[ntl] = __builtin_amdgcn_mfma_f32_16x16x32_bf16(af, bf, acc[ntl], 0, 0, 0);
        }
    }

    float pb[4]; bool cv[4];
#pragma unroll
    for (int ntl = 0; ntl < 4; ++ntl){
        const int c = ntl * 16 + l15;
        cv[ntl] = (c < L_);
        pb[ntl] = cv[ntl] ? projB[c] : 0.f;
    }

#pragma unroll
    for (int r = 0; r < 4; ++r){
        const int row = row0 + quad * 4 + r;
        const int b = row >> 9, t = row & 511;
        const int len = lengths[b];
        const bool valid = (t < len);

        float lv[4];
#pragma unroll
        for (int ntl = 0; ntl < 4; ++ntl)
            lv[ntl] = fmaxf(acc[ntl][r] + pb[ntl], 0.f);   // relu(logits)

        float mx = -1e30f;
#pragma unroll
        for (int ntl = 0; ntl < 4; ++ntl) if (cv[ntl]) mx = fmaxf(mx, lv[ntl]);
        mx = qredmax(mx);
        float se = 0.f;
#pragma unroll
        for (int ntl = 0; ntl < 4; ++ntl) if (cv[ntl]) se += expf(lv[ntl] - mx);
        se = qredsum(se);
        const int lbl = a[row];
        float cand = 0.f;
#pragma unroll
        for (int ntl = 0; ntl < 4; ++ntl) if (ntl * 16 + l15 == lbl) cand = lv[ntl];
        const float llbl = qredsum(cand);

        if (valid && l15 == 0){
            const float xent = logf(se) + mx - llbl;      // -log_softmax[label]
            atomicAdd(out, xent / ((float)len * 32.0f));
        }
    }
}

// ---------------------------------------------------------------- launch
extern "C" void kernel_launch(void* const* d_in, const int* in_sizes, int n_in,
                              void* d_out, int out_size, void* d_ws, size_t ws_size,
                              hipStream_t stream)
{
    const int*   q   = (const int*)d_in[0];
    const int*   a   = (const int*)d_in[1];
    const int*   len = (const int*)d_in[2];
    const float* we  = (const float*)d_in[3];
    const float* lW  = (const float*)d_in[4];
    const float* lB  = (const float*)d_in[5];
    const float* pW  = (const float*)d_in[6];
    const float* pB  = (const float*)d_in[7];
    float* out = (float*)d_out;

    unsigned char* ws = (unsigned char*)d_ws;
    unsigned int*   setup = (unsigned int*)ws;                       // 4 KiB
    unsigned int*   flags = (unsigned int*)(ws + 4096);              // 512*32*4 = 64 KiB
    unsigned short* h_all = (unsigned short*)(ws + 4096 + 65536);    // 513*32*512*2 B
    unsigned short* Wt    = (unsigned short*)(ws + 4096 + 65536 + (size_t)(T_ + 1) * B_ * H_ * 2);

    init_kernel<<<dim3(128), dim3(256), 0, stream>>>(pW, out, setup, flags, h_all, Wt);

    {
        const int* q_ = q; const int* len_ = len; const float* we_ = we;
        const float* lW_ = lW; const float* lB_ = lB;
        unsigned short* h_ = h_all; unsigned int* f_ = flags; unsigned int* s_ = setup;
        void* args[] = { (void*)&q_, (void*)&len_, (void*)&we_, (void*)&lW_,
                         (void*)&lB_, (void*)&h_, (void*)&f_, (void*)&s_ };
        hipLaunchCooperativeKernel((void*)lstm_kernel, dim3(NGRID), dim3(256),
                                   args, 0, stream);
    }

    loss_kernel<<<dim3(256), dim3(256), 0, stream>>>(a, len, pB, h_all, Wt, out);
}